// Round 7
// baseline (4686.765 us; speedup 1.0000x reference)
//
#include <hip/hip_runtime.h>
#include <hip/hip_fp16.h>

#define B_  64
#define T_  512
#define D_  512
#define H_  1024
#define ZC_ 4096   // 4*H
#define K_  1536   // D + H
#define KH_ 768    // K/2 per wave
#define HP_ 1032   // AldsH pitch in f16 (1024 + 8; rows 16B-aligned)

typedef _Float16 f16;
typedef __attribute__((ext_vector_type(8))) _Float16 f16x8;
typedef __attribute__((ext_vector_type(4))) float   f32x4;
typedef unsigned long long u64;

// ---------------------------------------------------------------------------
// Kernel 1: zero h-buffer (2 banks) + c-buffer + barrier counters
// ---------------------------------------------------------------------------
__global__ void init_state(uint4* __restrict__ p, int n16) {
    int i = blockIdx.x * blockDim.x + threadIdx.x;
    if (i < n16) p[i] = make_uint4(0u, 0u, 0u, 0u);
}

// ---------------------------------------------------------------------------
// Kernel 2: build Wt[c][k] (f16, column-major): k<512 -> Wi[k][c],
// k>=512 -> Wh[k-512][c].  Tiled LDS transpose, coalesced both sides.
// ---------------------------------------------------------------------------
__global__ void build_wt(const float* __restrict__ Wi, const float* __restrict__ Wh,
                         f16* __restrict__ Wt) {
    __shared__ float lds[64][65];
    const int ci = blockIdx.x;
    const int ki = blockIdx.y;
    const int tx = threadIdx.x & 63;
    const int ty = threadIdx.x >> 6;

    #pragma unroll
    for (int r = 0; r < 16; ++r) {
        int kk = ki * 64 + ty * 16 + r;
        int c  = ci * 64 + tx;
        float v = (kk < D_) ? Wi[(size_t)kk * ZC_ + c]
                            : Wh[(size_t)(kk - D_) * ZC_ + c];
        lds[ty * 16 + r][tx] = v;
    }
    __syncthreads();
    #pragma unroll
    for (int r = 0; r < 16; ++r) {
        int c_local = ty * 16 + r;
        int c  = ci * 64 + c_local;
        int kk = ki * 64 + tx;
        Wt[(size_t)c * K_ + kk] = (f16)lds[tx][c_local];
    }
}

// ---------------------------------------------------------------------------
// Kernel 3: LSTM span. 256 blocks x 512 threads (8 waves).
// Block bid -> group g=(bid&7)>>1 (batches g*16..+15, XCD pair {2g,2g+1}),
//              ng=((bid>>3)<<1)|(bid&1) (h-cols ng*16..+15).
// Wave w: gate q=w&3, K-half kh=w>>2; W fragment in 96 VGPRs (loaded once).
// x A-fragments in registers (xfrag[16], f32->f16 converted during the
// barrier spin window by the kh=0 waves) -> x never touches LDS; LDS holds
// only the h panel (16 x 1024 f16 = 4096 u64, staged 8 u64/thread) + zlds.
// Barrier: single fetch_add counter + lane-0 poll (round-4 structure; the
// slot-array barrier regressed: 64-line polls saturated the coherence point).
// ---------------------------------------------------------------------------
__global__ __launch_bounds__(512, 2) void lstm_span(
    const float* __restrict__ x,   // [B][T][D] f32
    const f16* __restrict__ Wt,    // [4096][1536] f16 (column-major weights)
    const float* __restrict__ bias,// [4096] f32
    f16* __restrict__ hbuf,        // [2][B][H] f16 (agent-atomic access only)
    float* __restrict__ cbuf,      // [B][H] f32
    unsigned* __restrict__ cnt,    // [4] barrier counters, 256B apart
    float* __restrict__ out,       // [B][T][H] f32
    int t0, int t1)
{
    const int bid = blockIdx.x;
    const int g   = (bid & 7) >> 1;                  // batch group 0..3
    const int ng  = ((bid >> 3) << 1) | (bid & 1);   // col group 0..63

    const int tid  = threadIdx.x;
    const int wave = tid >> 6;            // 0..7
    const int lane = tid & 63;
    const int q    = wave & 3;            // gate
    const int kh   = wave >> 2;           // K-half

    __shared__ __align__(16) f16 AldsH[16][HP_];     // h panel only (33 KB)
    __shared__ float zlds[8][16][17];                // [wave][row][col]

    const int jj = tid & 15;
    const int bl = tid >> 4;              // gate-thread batch row when tid<256
    const float bi  = bias[0 * H_ + ng * 16 + jj];
    const float bff = bias[1 * H_ + ng * 16 + jj];
    const float bg  = bias[2 * H_ + ng * 16 + jj];
    const float bo  = bias[3 * H_ + ng * 16 + jj];

    const int r  = lane & 15;             // A row
    const int a8 = (lane >> 4) * 8;       // A k sub-offset
    const int b0 = g * 16;

    // ---- W fragment -> registers (once). col = q*H + ng*16 + r
    const f16* Wcol = Wt + (size_t)(q * H_ + ng * 16 + r) * K_ + kh * KH_ + a8;
    f16x8 wreg[24];
    #pragma unroll
    for (int ks = 0; ks < 24; ++ks)
        wreg[ks] = *(const f16x8*)(Wcol + ks * 32);

    // cell state: one (batch,col) per thread (gate threads tid<256 only)
    const size_t cidx = (size_t)(b0 + (bl & 15)) * H_ + ng * 16 + jj;
    float c = (tid < 256) ? cbuf[cidx] : 0.f;

    unsigned* mycnt = cnt + g * 64;       // 256B-spaced counters

    // ---- x A-fragments in registers (kh=0 waves): 16 frags = 64 VGPR.
    // frag ks covers k = ks*32 + a8 .. +7  (k < 512 -> d = k)
    f16x8 xfrag[16];
    const float* xrow = x + (size_t)(b0 + r) * T_ * D_ + a8;
    auto fetch_x = [&](int t) {
        const float* src0 = xrow + (size_t)t * D_;
        #pragma unroll
        for (int ks = 0; ks < 16; ++ks) {
            float4 v0 = ((const float4*)(src0 + ks * 32))[0];
            float4 v1 = ((const float4*)(src0 + ks * 32))[1];
            f16x8 o;
            o[0] = (f16)v0.x; o[1] = (f16)v0.y; o[2] = (f16)v0.z; o[3] = (f16)v0.w;
            o[4] = (f16)v1.x; o[5] = (f16)v1.y; o[6] = (f16)v1.z; o[7] = (f16)v1.w;
            xfrag[ks] = o;
        }
    };
    if (tid < 256) fetch_x(t0);   // pre-loop

    for (int t = t0; t < t1; ++t) {
        // ---- stage h_prev (bank t&1) via uncached u64 agent loads -> LDS
        // 16 rows * 256 u64 = 4096 u64, 8 per thread
        const f16* hprev = hbuf + (size_t)(t & 1) * (B_ * H_);
        #pragma unroll
        for (int i = 0; i < 8; ++i) {
            int ch  = tid + i * 512;
            int row = ch >> 8;              // 0..15
            int cu  = ch & 255;             // 0..255 -> cols cu*4 .. cu*4+3
            u64 v = __hip_atomic_load(
                (u64*)(hprev + (size_t)(b0 + row) * H_ + cu * 4),
                __ATOMIC_RELAXED, __HIP_MEMORY_SCOPE_AGENT);
            *(u64*)(&AldsH[row][cu * 4]) = v;
        }
        __syncthreads();

        // ---- GEMM: 16x16 tile, K-half=768; A from regs (x) + LDS (h)
        f32x4 acc0 = {0,0,0,0}, acc1 = {0,0,0,0}, acc2 = {0,0,0,0}, acc3 = {0,0,0,0};
        if (kh == 0) {
            // k 0..511 = x (registers), k 512..767 = h cols 0..255 (LDS)
            #pragma unroll
            for (int ks = 0; ks < 16; ks += 4) {
                acc0 = __builtin_amdgcn_mfma_f32_16x16x32_f16(xfrag[ks + 0], wreg[ks + 0], acc0, 0, 0, 0);
                acc1 = __builtin_amdgcn_mfma_f32_16x16x32_f16(xfrag[ks + 1], wreg[ks + 1], acc1, 0, 0, 0);
                acc2 = __builtin_amdgcn_mfma_f32_16x16x32_f16(xfrag[ks + 2], wreg[ks + 2], acc2, 0, 0, 0);
                acc3 = __builtin_amdgcn_mfma_f32_16x16x32_f16(xfrag[ks + 3], wreg[ks + 3], acc3, 0, 0, 0);
            }
            #pragma unroll
            for (int ks = 16; ks < 24; ks += 4) {
                f16x8 a0 = *(const f16x8*)(&AldsH[r][(ks - 16) * 32 + a8]);
                acc0 = __builtin_amdgcn_mfma_f32_16x16x32_f16(a0, wreg[ks + 0], acc0, 0, 0, 0);
                f16x8 a1 = *(const f16x8*)(&AldsH[r][(ks - 15) * 32 + a8]);
                acc1 = __builtin_amdgcn_mfma_f32_16x16x32_f16(a1, wreg[ks + 1], acc1, 0, 0, 0);
                f16x8 a2 = *(const f16x8*)(&AldsH[r][(ks - 14) * 32 + a8]);
                acc2 = __builtin_amdgcn_mfma_f32_16x16x32_f16(a2, wreg[ks + 2], acc2, 0, 0, 0);
                f16x8 a3 = *(const f16x8*)(&AldsH[r][(ks - 13) * 32 + a8]);
                acc3 = __builtin_amdgcn_mfma_f32_16x16x32_f16(a3, wreg[ks + 3], acc3, 0, 0, 0);
            }
        } else {
            // k 768..1535 = h cols 256..1023 (LDS)
            #pragma unroll
            for (int ks = 0; ks < 24; ks += 4) {
                f16x8 a0 = *(const f16x8*)(&AldsH[r][256 + (ks + 0) * 32 + a8]);
                acc0 = __builtin_amdgcn_mfma_f32_16x16x32_f16(a0, wreg[ks + 0], acc0, 0, 0, 0);
                f16x8 a1 = *(const f16x8*)(&AldsH[r][256 + (ks + 1) * 32 + a8]);
                acc1 = __builtin_amdgcn_mfma_f32_16x16x32_f16(a1, wreg[ks + 1], acc1, 0, 0, 0);
                f16x8 a2 = *(const f16x8*)(&AldsH[r][256 + (ks + 2) * 32 + a8]);
                acc2 = __builtin_amdgcn_mfma_f32_16x16x32_f16(a2, wreg[ks + 2], acc2, 0, 0, 0);
                f16x8 a3 = *(const f16x8*)(&AldsH[r][256 + (ks + 3) * 32 + a8]);
                acc3 = __builtin_amdgcn_mfma_f32_16x16x32_f16(a3, wreg[ks + 3], acc3, 0, 0, 0);
            }
        }
        f32x4 z = (acc0 + acc1) + (acc2 + acc3);

        // ---- C/D layout: col = lane&15, row = (lane>>4)*4 + rr
        #pragma unroll
        for (int rr = 0; rr < 4; ++rr)
            zlds[wave][(lane >> 4) * 4 + rr][lane & 15] = z[rr];
        __syncthreads();

        // ---- fused gates + state update (threads 0..255; sum both K-halves)
        if (tid < 256) {
            float zi = zlds[0][bl][jj] + zlds[4][bl][jj] + bi;
            float zf = zlds[1][bl][jj] + zlds[5][bl][jj] + bff;
            float zg = zlds[2][bl][jj] + zlds[6][bl][jj] + bg;
            float zo = zlds[3][bl][jj] + zlds[7][bl][jj] + bo;
            float ig = 1.f / (1.f + __expf(-zi));
            float fg = 1.f / (1.f + __expf(-zf));
            float gg = 2.f / (1.f + __expf(-2.f * zg)) - 1.f;
            float og = 1.f / (1.f + __expf(-zo));
            float nc = fg * c + ig * gg;
            float th = 2.f / (1.f + __expf(-2.f * nc)) - 1.f;
            float nh = og * th;
            c = nc;
            const int bglob = b0 + bl;
            const int col   = ng * 16 + jj;

            // h first (on the inter-block critical path), out second
            unsigned hv = (unsigned)__builtin_bit_cast(unsigned short, (f16)nh);
            unsigned h1 = __shfl_xor(hv, 1);
            unsigned h2 = __shfl_xor(hv, 2);
            unsigned h3 = __shfl_xor(hv, 3);
            if ((jj & 3) == 0) {
                u64 pk = (u64)hv | ((u64)h1 << 16) | ((u64)h2 << 32) | ((u64)h3 << 48);
                __hip_atomic_store(
                    (u64*)(hbuf + (size_t)((t + 1) & 1) * (B_ * H_)
                                + (size_t)bglob * H_ + col),
                    pk, __ATOMIC_RELAXED, __HIP_MEMORY_SCOPE_AGENT);
            }
            out[((size_t)bglob * T_ + t) * H_ + col] = nh;
        }

        // ---- barrier (persistent mode only); x_{t+1} prefetch hides in spin
        if (t + 1 < t1) {
            __syncthreads();   // drains vmcnt: h stores visible device-wide
            if (tid == 0)      // arrive first
                __hip_atomic_fetch_add(mycnt, 1u, __ATOMIC_RELAXED,
                                       __HIP_MEMORY_SCOPE_AGENT);
            if (tid < 256)     // kh0 waves: next x slice -> registers
                fetch_x(t + 1);
            if (tid == 0) {    // then poll
                const unsigned target = 64u * (unsigned)(t + 1);
                while (__hip_atomic_load(mycnt, __ATOMIC_RELAXED,
                                         __HIP_MEMORY_SCOPE_AGENT) < target)
                    __builtin_amdgcn_s_sleep(1);
            }
            __syncthreads();
        }
    }
    if (tid < 256) cbuf[cidx] = c;   // persist cell state across span launches
}

// ---------------------------------------------------------------------------
extern "C" void kernel_launch(void* const* d_in, const int* in_sizes, int n_in,
                              void* d_out, int out_size, void* d_ws, size_t ws_size,
                              hipStream_t stream) {
    const float* x    = (const float*)d_in[0];
    const float* Wi   = (const float*)d_in[1];
    const float* Wh   = (const float*)d_in[2];
    const float* bias = (const float*)d_in[3];
    float* out = (float*)d_out;

    // workspace: Wt | hbuf(2 banks) | cbuf | counters
    const size_t wt_bytes = (size_t)ZC_ * K_ * sizeof(f16);    // 12,582,912
    const size_t hb_bytes = (size_t)2 * B_ * H_ * sizeof(f16); //    262,144
    const size_t cb_bytes = (size_t)B_ * H_ * sizeof(float);   //    262,144
    const size_t cn_bytes = 4096;
    if (ws_size < wt_bytes + hb_bytes + cb_bytes + cn_bytes) return;

    f16*      Wt   = (f16*)d_ws;
    f16*      hbuf = (f16*)((char*)d_ws + wt_bytes);
    float*    cbuf = (float*)((char*)d_ws + wt_bytes + hb_bytes);
    unsigned* cnt  = (unsigned*)((char*)d_ws + wt_bytes + hb_bytes + cb_bytes);

    // zero hbuf + cbuf + counters (contiguous region)
    const int n16 = (int)((hb_bytes + cb_bytes + cn_bytes) / 16);
    init_state<<<(n16 + 255) / 256, 256, 0, stream>>>((uint4*)hbuf, n16);
    build_wt<<<dim3(ZC_ / 64, K_ / 64), 256, 0, stream>>>(Wi, Wh, Wt);

    int t0 = 0, t1 = T_;
    void* args[] = { (void*)&x, (void*)&Wt, (void*)&bias, (void*)&hbuf,
                     (void*)&cbuf, (void*)&cnt, (void*)&out, (void*)&t0, (void*)&t1 };
    hipError_t e = hipLaunchCooperativeKernel((const void*)lstm_span,
                                              dim3(256), dim3(512), args, 0, stream);
    if (e != hipSuccess) {
        (void)hipGetLastError();
        // fallback: one regular launch per timestep (no in-kernel barrier)
        for (int t = 0; t < T_; ++t) {
            lstm_span<<<256, 512, 0, stream>>>(x, Wt, bias, hbuf, cbuf, cnt, out, t, t + 1);
        }
    }
}

// Round 9
// 1731.683 us; speedup vs baseline: 2.7065x; 2.7065x over previous
//
#include <hip/hip_runtime.h>
#include <hip/hip_fp16.h>

#define B_  64
#define T_  512
#define D_  512
#define H_  1024
#define ZC_ 4096   // 4*H
#define K_  1536   // D + H
#define XP_ 520    // AldsX pitch in f16 (512 + 8)
#define HP_ 1032   // AldsH pitch in f16 (1024 + 8)

typedef _Float16 f16;
typedef __attribute__((ext_vector_type(8))) _Float16 f16x8;
typedef __attribute__((ext_vector_type(4))) float   f32x4;
typedef unsigned long long u64;

// ---------------------------------------------------------------------------
// Kernel 1: zero h-buffer (2 banks) + c-buffer + barrier counters
// ---------------------------------------------------------------------------
__global__ void init_state(uint4* __restrict__ p, int n16) {
    int i = blockIdx.x * blockDim.x + threadIdx.x;
    if (i < n16) p[i] = make_uint4(0u, 0u, 0u, 0u);
}

// ---------------------------------------------------------------------------
// Kernel 2: build Wt[c][k] (f16, column-major): k<512 -> Wi[k][c],
// k>=512 -> Wh[k-512][c].  Tiled LDS transpose, coalesced both sides.
// ---------------------------------------------------------------------------
__global__ void build_wt(const float* __restrict__ Wi, const float* __restrict__ Wh,
                         f16* __restrict__ Wt) {
    __shared__ float lds[64][65];
    const int ci = blockIdx.x;
    const int ki = blockIdx.y;
    const int tx = threadIdx.x & 63;
    const int ty = threadIdx.x >> 6;

    #pragma unroll
    for (int r = 0; r < 16; ++r) {
        int kk = ki * 64 + ty * 16 + r;
        int c  = ci * 64 + tx;
        float v = (kk < D_) ? Wi[(size_t)kk * ZC_ + c]
                            : Wh[(size_t)(kk - D_) * ZC_ + c];
        lds[ty * 16 + r][tx] = v;
    }
    __syncthreads();
    #pragma unroll
    for (int r = 0; r < 16; ++r) {
        int c_local = ty * 16 + r;
        int c  = ci * 64 + c_local;
        int kk = ki * 64 + tx;
        Wt[(size_t)c * K_ + kk] = (f16)lds[tx][c_local];
    }
}

// ---------------------------------------------------------------------------
// Kernel 3: LSTM span. 256 blocks x 512 threads (8 waves).
// Block bid -> group g=(bid&7)>>1 (batches g*16..+15, XCD pair {2g,2g+1}),
//              ng=((bid>>3)<<1)|(bid&1) (h-cols ng*16..+15).
// Wave w = (q = w&3 gate, p = w>>2 K-part). Balanced split-phase K map:
//   x-part : k in [p*256,(p+1)*256)          -> 8 MFMAs (LDS x + W regs)
//   h-part : k in [512+p*512, 512+(p+1)*512) -> 16 MFMAs (LDS h + W regs)
// Step schedule: issue 8 uncached h-loads to REGISTERS -> x-part MFMAs run
// under the load latency -> h regs -> LDS -> sync -> h-part MFMAs.
// Spin window (round-4 barrier, fetch_add + lane-0 poll, s_sleep(2)):
// waves 1-7 stage x_{t+1} -> LDS; gate threads store `out` (off the
// pre-arrive drain); no extra coherence-point traffic (rounds 5/7 lesson).
// BUGFIX vs round 8: __syncthreads() after the pre-loop stage_x (the first
// iteration's x-part GEMM raced the prologue staging -> NaN).
// ---------------------------------------------------------------------------
__global__ __launch_bounds__(512, 2) void lstm_span(
    const float* __restrict__ x,   // [B][T][D] f32
    const f16* __restrict__ Wt,    // [4096][1536] f16 (column-major weights)
    const float* __restrict__ bias,// [4096] f32
    f16* __restrict__ hbuf,        // [2][B][H] f16 (agent-atomic access only)
    float* __restrict__ cbuf,      // [B][H] f32
    unsigned* __restrict__ cnt,    // [4] barrier counters, 256B apart
    float* __restrict__ out,       // [B][T][H] f32
    int t0, int t1)
{
    const int bid = blockIdx.x;
    const int g   = (bid & 7) >> 1;                  // batch group 0..3
    const int ng  = ((bid >> 3) << 1) | (bid & 1);   // col group 0..63

    const int tid  = threadIdx.x;
    const int wave = tid >> 6;            // 0..7
    const int lane = tid & 63;
    const int q    = wave & 3;            // gate
    const int p    = wave >> 2;           // K-part

    __shared__ __align__(16) f16 AldsX[16][XP_];     // x panel (16.6 KB)
    __shared__ __align__(16) f16 AldsH[16][HP_];     // h panel (33 KB)
    __shared__ float zlds[8][16][17];                // [wave][row][col]

    const int jj = tid & 15;
    const int bl = tid >> 4;              // gate-thread batch row when tid<256
    const float bi  = bias[0 * H_ + ng * 16 + jj];
    const float bff = bias[1 * H_ + ng * 16 + jj];
    const float bg  = bias[2 * H_ + ng * 16 + jj];
    const float bo  = bias[3 * H_ + ng * 16 + jj];

    const int r  = lane & 15;             // A row
    const int a8 = (lane >> 4) * 8;       // A k sub-offset within 32-k block
    const int b0 = g * 16;

    // ---- W fragments -> registers (once). col c = q*H + ng*16 + r
    const f16* Wc = Wt + (size_t)(q * H_ + ng * 16 + r) * K_;
    f16x8 wregX[8];                       // x-part: k = p*256 + ks*32 + a8
    #pragma unroll
    for (int ks = 0; ks < 8; ++ks)
        wregX[ks] = *(const f16x8*)(Wc + p * 256 + ks * 32 + a8);
    f16x8 wregH[16];                      // h-part: k = 512 + p*512 + ks*32 + a8
    #pragma unroll
    for (int ks = 0; ks < 16; ++ks)
        wregH[ks] = *(const f16x8*)(Wc + 512 + p * 512 + ks * 32 + a8);

    // cell state: one (batch,col) per thread (gate threads tid<256 only)
    const size_t cidx = (size_t)(b0 + (bl & 15)) * H_ + ng * 16 + jj;
    float c = (tid < 256) ? cbuf[cidx] : 0.f;

    unsigned* mycnt = cnt + g * 64;       // 256B-spaced counters

    // ---- stage x_t slice (f32->f16) into AldsX; 1024 8-elem chunks
    auto stage_x = [&](int t, int tbase, int nthr) {
        for (int ch = tid - tbase; ch < 1024; ch += nthr) {
            if (ch < 0) continue;
            int row = ch >> 6;
            int kc  = (ch & 63) * 8;
            const float* src = x + ((size_t)(b0 + row) * T_ + t) * D_ + kc;
            float4 v0 = ((const float4*)src)[0];
            float4 v1 = ((const float4*)src)[1];
            f16x8 o;
            o[0] = (f16)v0.x; o[1] = (f16)v0.y; o[2] = (f16)v0.z; o[3] = (f16)v0.w;
            o[4] = (f16)v1.x; o[5] = (f16)v1.y; o[6] = (f16)v1.z; o[7] = (f16)v1.w;
            *(f16x8*)(&AldsX[row][kc]) = o;
        }
    };

    stage_x(t0, 0, 512);   // pre-loop: all threads stage x_{t0}
    __syncthreads();       // BUGFIX: first x-part GEMM must see staged AldsX

    for (int t = t0; t < t1; ++t) {
        // ---- 1. issue h_prev loads (uncached agent u64) into REGISTERS
        // 16 rows * 256 u64 = 4096 u64, 8 per thread
        const f16* hprev = hbuf + (size_t)(t & 1) * (B_ * H_);
        u64 hreg[8];
        #pragma unroll
        for (int i = 0; i < 8; ++i) {
            int ch  = tid + i * 512;
            int row = ch >> 8;              // 0..15
            int cu  = ch & 255;             // cols cu*4 .. cu*4+3
            hreg[i] = __hip_atomic_load(
                (u64*)(hprev + (size_t)(b0 + row) * H_ + cu * 4),
                __ATOMIC_RELAXED, __HIP_MEMORY_SCOPE_AGENT);
        }

        // ---- 2. x-part GEMM (8 MFMAs) under the h-load latency
        f32x4 acc0 = {0,0,0,0}, acc1 = {0,0,0,0}, acc2 = {0,0,0,0}, acc3 = {0,0,0,0};
        #pragma unroll
        for (int ks = 0; ks < 8; ks += 4) {
            f16x8 a0 = *(const f16x8*)(&AldsX[r][p * 256 + (ks + 0) * 32 + a8]);
            acc0 = __builtin_amdgcn_mfma_f32_16x16x32_f16(a0, wregX[ks + 0], acc0, 0, 0, 0);
            f16x8 a1 = *(const f16x8*)(&AldsX[r][p * 256 + (ks + 1) * 32 + a8]);
            acc1 = __builtin_amdgcn_mfma_f32_16x16x32_f16(a1, wregX[ks + 1], acc1, 0, 0, 0);
            f16x8 a2 = *(const f16x8*)(&AldsX[r][p * 256 + (ks + 2) * 32 + a8]);
            acc2 = __builtin_amdgcn_mfma_f32_16x16x32_f16(a2, wregX[ks + 2], acc2, 0, 0, 0);
            f16x8 a3 = *(const f16x8*)(&AldsX[r][p * 256 + (ks + 3) * 32 + a8]);
            acc3 = __builtin_amdgcn_mfma_f32_16x16x32_f16(a3, wregX[ks + 3], acc3, 0, 0, 0);
        }

        // ---- 3. h regs -> LDS, sync
        #pragma unroll
        for (int i = 0; i < 8; ++i) {
            int ch  = tid + i * 512;
            int row = ch >> 8;
            int cu  = ch & 255;
            *(u64*)(&AldsH[row][cu * 4]) = hreg[i];
        }
        __syncthreads();

        // ---- 4. h-part GEMM (16 MFMAs): h cols p*512 .. p*512+511
        #pragma unroll
        for (int ks = 0; ks < 16; ks += 4) {
            f16x8 a0 = *(const f16x8*)(&AldsH[r][p * 512 + (ks + 0) * 32 + a8]);
            acc0 = __builtin_amdgcn_mfma_f32_16x16x32_f16(a0, wregH[ks + 0], acc0, 0, 0, 0);
            f16x8 a1 = *(const f16x8*)(&AldsH[r][p * 512 + (ks + 1) * 32 + a8]);
            acc1 = __builtin_amdgcn_mfma_f32_16x16x32_f16(a1, wregH[ks + 1], acc1, 0, 0, 0);
            f16x8 a2 = *(const f16x8*)(&AldsH[r][p * 512 + (ks + 2) * 32 + a8]);
            acc2 = __builtin_amdgcn_mfma_f32_16x16x32_f16(a2, wregH[ks + 2], acc2, 0, 0, 0);
            f16x8 a3 = *(const f16x8*)(&AldsH[r][p * 512 + (ks + 3) * 32 + a8]);
            acc3 = __builtin_amdgcn_mfma_f32_16x16x32_f16(a3, wregH[ks + 3], acc3, 0, 0, 0);
        }
        f32x4 z = (acc0 + acc1) + (acc2 + acc3);

        // ---- C/D layout: col = lane&15, row = (lane>>4)*4 + rr
        #pragma unroll
        for (int rr = 0; rr < 4; ++rr)
            zlds[wave][(lane >> 4) * 4 + rr][lane & 15] = z[rr];
        __syncthreads();

        // ---- fused gates + state update (threads 0..255; sum both K-parts)
        float nh = 0.f;
        if (tid < 256) {
            float zi = zlds[0][bl][jj] + zlds[4][bl][jj] + bi;
            float zf = zlds[1][bl][jj] + zlds[5][bl][jj] + bff;
            float zg = zlds[2][bl][jj] + zlds[6][bl][jj] + bg;
            float zo = zlds[3][bl][jj] + zlds[7][bl][jj] + bo;
            float ig = 1.f / (1.f + __expf(-zi));
            float fg = 1.f / (1.f + __expf(-zf));
            float gg = 2.f / (1.f + __expf(-2.f * zg)) - 1.f;
            float og = 1.f / (1.f + __expf(-zo));
            float nc = fg * c + ig * gg;
            float th = 2.f / (1.f + __expf(-2.f * nc)) - 1.f;
            nh = og * th;
            c = nc;

            // h-store only (the inter-block dependency); out deferred to spin
            unsigned hv = (unsigned)__builtin_bit_cast(unsigned short, (f16)nh);
            unsigned h1 = __shfl_xor(hv, 1);
            unsigned h2 = __shfl_xor(hv, 2);
            unsigned h3 = __shfl_xor(hv, 3);
            if ((jj & 3) == 0) {
                u64 pk = (u64)hv | ((u64)h1 << 16) | ((u64)h2 << 32) | ((u64)h3 << 48);
                __hip_atomic_store(
                    (u64*)(hbuf + (size_t)((t + 1) & 1) * (B_ * H_)
                                + (size_t)(b0 + bl) * H_ + ng * 16 + jj),
                    pk, __ATOMIC_RELAXED, __HIP_MEMORY_SCOPE_AGENT);
            }
        }

        // ---- barrier + spin-window work (persistent mode only)
        if (t + 1 < t1) {
            __syncthreads();   // drains h-stores (out not yet issued)
            if (tid == 0)      // arrive
                __hip_atomic_fetch_add(mycnt, 1u, __ATOMIC_RELAXED,
                                       __HIP_MEMORY_SCOPE_AGENT);
            if (tid < 256)     // out-store completes during the spin
                out[((size_t)(b0 + bl) * T_ + t) * H_ + ng * 16 + jj] = nh;
            if (tid >= 64)     // waves 1..7: stage x_{t+1}
                stage_x(t + 1, 64, 448);
            if (tid == 0) {    // poll
                const unsigned target = 64u * (unsigned)(t + 1);
                while (__hip_atomic_load(mycnt, __ATOMIC_RELAXED,
                                         __HIP_MEMORY_SCOPE_AGENT) < target)
                    __builtin_amdgcn_s_sleep(2);
            }
            __syncthreads();
        } else if (tid < 256) {
            out[((size_t)(b0 + bl) * T_ + t) * H_ + ng * 16 + jj] = nh;
        }
    }
    if (tid < 256) cbuf[cidx] = c;   // persist cell state across span launches
}

// ---------------------------------------------------------------------------
extern "C" void kernel_launch(void* const* d_in, const int* in_sizes, int n_in,
                              void* d_out, int out_size, void* d_ws, size_t ws_size,
                              hipStream_t stream) {
    const float* x    = (const float*)d_in[0];
    const float* Wi   = (const float*)d_in[1];
    const float* Wh   = (const float*)d_in[2];
    const float* bias = (const float*)d_in[3];
    float* out = (float*)d_out;

    // workspace: Wt | hbuf(2 banks) | cbuf | counters
    const size_t wt_bytes = (size_t)ZC_ * K_ * sizeof(f16);    // 12,582,912
    const size_t hb_bytes = (size_t)2 * B_ * H_ * sizeof(f16); //    262,144
    const size_t cb_bytes = (size_t)B_ * H_ * sizeof(float);   //    262,144
    const size_t cn_bytes = 4096;
    if (ws_size < wt_bytes + hb_bytes + cb_bytes + cn_bytes) return;

    f16*      Wt   = (f16*)d_ws;
    f16*      hbuf = (f16*)((char*)d_ws + wt_bytes);
    float*    cbuf = (float*)((char*)d_ws + wt_bytes + hb_bytes);
    unsigned* cnt  = (unsigned*)((char*)d_ws + wt_bytes + hb_bytes + cb_bytes);

    // zero hbuf + cbuf + counters (contiguous region)
    const int n16 = (int)((hb_bytes + cb_bytes + cn_bytes) / 16);
    init_state<<<(n16 + 255) / 256, 256, 0, stream>>>((uint4*)hbuf, n16);
    build_wt<<<dim3(ZC_ / 64, K_ / 64), 256, 0, stream>>>(Wi, Wh, Wt);

    int t0 = 0, t1 = T_;
    void* args[] = { (void*)&x, (void*)&Wt, (void*)&bias, (void*)&hbuf,
                     (void*)&cbuf, (void*)&cnt, (void*)&out, (void*)&t0, (void*)&t1 };
    hipError_t e = hipLaunchCooperativeKernel((const void*)lstm_span,
                                              dim3(256), dim3(512), args, 0, stream);
    if (e != hipSuccess) {
        (void)hipGetLastError();
        // fallback: one regular launch per timestep (no in-kernel barrier)
        for (int t = 0; t < T_; ++t) {
            lstm_span<<<256, 512, 0, stream>>>(x, Wt, bias, hbuf, cbuf, cnt, out, t, t + 1);
        }
    }
}

// Round 10
// 1692.598 us; speedup vs baseline: 2.7690x; 1.0231x over previous
//
#include <hip/hip_runtime.h>
#include <hip/hip_fp16.h>

#define B_  64
#define T_  512
#define D_  512
#define H_  1024
#define ZC_ 4096   // 4*H
#define K_  1536   // D + H
#define XP_ 520    // AldsX pitch in f16 (512 + 8)
#define HP_ 1032   // AldsH pitch in f16 (1024 + 8)
#define LOG2E 1.4426950408889634f

typedef _Float16 f16;
typedef __attribute__((ext_vector_type(8))) _Float16 f16x8;
typedef __attribute__((ext_vector_type(4))) float   f32x4;
typedef unsigned long long u64;

// fast sigmoid / tanh: v_exp_f32 (2^x) + v_rcp_f32, saturate correctly at +-inf
__device__ __forceinline__ float fsigmoid(float v) {
    return __builtin_amdgcn_rcpf(1.f + __builtin_amdgcn_exp2f(-LOG2E * v));
}
__device__ __forceinline__ float ftanh(float v) {
    return 2.f * __builtin_amdgcn_rcpf(1.f + __builtin_amdgcn_exp2f(-2.f * LOG2E * v)) - 1.f;
}

// ---------------------------------------------------------------------------
// Kernel 1: zero h-buffer (2 banks) + c-buffer + barrier counters
// ---------------------------------------------------------------------------
__global__ void init_state(uint4* __restrict__ p, int n16) {
    int i = blockIdx.x * blockDim.x + threadIdx.x;
    if (i < n16) p[i] = make_uint4(0u, 0u, 0u, 0u);
}

// ---------------------------------------------------------------------------
// Kernel 2: build Wt[c][k] (f16, column-major): k<512 -> Wi[k][c],
// k>=512 -> Wh[k-512][c].  Tiled LDS transpose, coalesced both sides.
// ---------------------------------------------------------------------------
__global__ void build_wt(const float* __restrict__ Wi, const float* __restrict__ Wh,
                         f16* __restrict__ Wt) {
    __shared__ float lds[64][65];
    const int ci = blockIdx.x;
    const int ki = blockIdx.y;
    const int tx = threadIdx.x & 63;
    const int ty = threadIdx.x >> 6;

    #pragma unroll
    for (int r = 0; r < 16; ++r) {
        int kk = ki * 64 + ty * 16 + r;
        int c  = ci * 64 + tx;
        float v = (kk < D_) ? Wi[(size_t)kk * ZC_ + c]
                            : Wh[(size_t)(kk - D_) * ZC_ + c];
        lds[ty * 16 + r][tx] = v;
    }
    __syncthreads();
    #pragma unroll
    for (int r = 0; r < 16; ++r) {
        int c_local = ty * 16 + r;
        int c  = ci * 64 + c_local;
        int kk = ki * 64 + tx;
        Wt[(size_t)c * K_ + kk] = (f16)lds[tx][c_local];
    }
}

// ---------------------------------------------------------------------------
// Kernel 3: LSTM span. 256 blocks x 512 threads (8 waves).
// Block bid -> group g=(bid&7)>>1 (batches g*16..+15, XCD pair {2g,2g+1}),
//              ng=((bid>>3)<<1)|(bid&1) (h-cols ng*16..+15).
// Wave w = (q = w&3 gate, p = w>>2 K-part). Balanced split-phase K map:
//   x-part : k in [p*256,(p+1)*256)          -> 8 MFMAs (LDS x + W regs)
//   h-part : k in [512+p*512, 512+(p+1)*512) -> 16 MFMAs (LDS h + W regs)
// Step schedule: issue 8 uncached h-loads to REGISTERS -> x-part MFMAs run
// under the load latency -> h regs -> LDS -> sync -> h-part MFMAs.
// Spin window (fetch_add + lane-0 poll, s_sleep(1)): waves 1-7 stage
// x_{t+1} -> LDS; gate threads store `out` (off the pre-arrive drain);
// no extra coherence-point traffic in the barrier window (rounds 5/7 lesson).
// Round-10 deltas vs round 9: s_sleep(2)->(1); gates use v_exp2/v_rcp
// (precise-div sequences removed from the serial gate chain).
// ---------------------------------------------------------------------------
__global__ __launch_bounds__(512, 2) void lstm_span(
    const float* __restrict__ x,   // [B][T][D] f32
    const f16* __restrict__ Wt,    // [4096][1536] f16 (column-major weights)
    const float* __restrict__ bias,// [4096] f32
    f16* __restrict__ hbuf,        // [2][B][H] f16 (agent-atomic access only)
    float* __restrict__ cbuf,      // [B][H] f32
    unsigned* __restrict__ cnt,    // [4] barrier counters, 256B apart
    float* __restrict__ out,       // [B][T][H] f32
    int t0, int t1)
{
    const int bid = blockIdx.x;
    const int g   = (bid & 7) >> 1;                  // batch group 0..3
    const int ng  = ((bid >> 3) << 1) | (bid & 1);   // col group 0..63

    const int tid  = threadIdx.x;
    const int wave = tid >> 6;            // 0..7
    const int lane = tid & 63;
    const int q    = wave & 3;            // gate
    const int p    = wave >> 2;           // K-part

    __shared__ __align__(16) f16 AldsX[16][XP_];     // x panel (16.6 KB)
    __shared__ __align__(16) f16 AldsH[16][HP_];     // h panel (33 KB)
    __shared__ float zlds[8][16][17];                // [wave][row][col]

    const int jj = tid & 15;
    const int bl = tid >> 4;              // gate-thread batch row when tid<256
    const float bi  = bias[0 * H_ + ng * 16 + jj];
    const float bff = bias[1 * H_ + ng * 16 + jj];
    const float bg  = bias[2 * H_ + ng * 16 + jj];
    const float bo  = bias[3 * H_ + ng * 16 + jj];

    const int r  = lane & 15;             // A row
    const int a8 = (lane >> 4) * 8;       // A k sub-offset within 32-k block
    const int b0 = g * 16;

    // ---- W fragments -> registers (once). col c = q*H + ng*16 + r
    const f16* Wc = Wt + (size_t)(q * H_ + ng * 16 + r) * K_;
    f16x8 wregX[8];                       // x-part: k = p*256 + ks*32 + a8
    #pragma unroll
    for (int ks = 0; ks < 8; ++ks)
        wregX[ks] = *(const f16x8*)(Wc + p * 256 + ks * 32 + a8);
    f16x8 wregH[16];                      // h-part: k = 512 + p*512 + ks*32 + a8
    #pragma unroll
    for (int ks = 0; ks < 16; ++ks)
        wregH[ks] = *(const f16x8*)(Wc + 512 + p * 512 + ks * 32 + a8);

    // cell state: one (batch,col) per thread (gate threads tid<256 only)
    const size_t cidx = (size_t)(b0 + (bl & 15)) * H_ + ng * 16 + jj;
    float c = (tid < 256) ? cbuf[cidx] : 0.f;

    unsigned* mycnt = cnt + g * 64;       // 256B-spaced counters

    // ---- stage x_t slice (f32->f16) into AldsX; 1024 8-elem chunks
    auto stage_x = [&](int t, int tbase, int nthr) {
        for (int ch = tid - tbase; ch < 1024; ch += nthr) {
            if (ch < 0) continue;
            int row = ch >> 6;
            int kc  = (ch & 63) * 8;
            const float* src = x + ((size_t)(b0 + row) * T_ + t) * D_ + kc;
            float4 v0 = ((const float4*)src)[0];
            float4 v1 = ((const float4*)src)[1];
            f16x8 o;
            o[0] = (f16)v0.x; o[1] = (f16)v0.y; o[2] = (f16)v0.z; o[3] = (f16)v0.w;
            o[4] = (f16)v1.x; o[5] = (f16)v1.y; o[6] = (f16)v1.z; o[7] = (f16)v1.w;
            *(f16x8*)(&AldsX[row][kc]) = o;
        }
    };

    stage_x(t0, 0, 512);   // pre-loop: all threads stage x_{t0}
    __syncthreads();       // first x-part GEMM must see staged AldsX

    for (int t = t0; t < t1; ++t) {
        // ---- 1. issue h_prev loads (uncached agent u64) into REGISTERS
        // 16 rows * 256 u64 = 4096 u64, 8 per thread
        const f16* hprev = hbuf + (size_t)(t & 1) * (B_ * H_);
        u64 hreg[8];
        #pragma unroll
        for (int i = 0; i < 8; ++i) {
            int ch  = tid + i * 512;
            int row = ch >> 8;              // 0..15
            int cu  = ch & 255;             // cols cu*4 .. cu*4+3
            hreg[i] = __hip_atomic_load(
                (u64*)(hprev + (size_t)(b0 + row) * H_ + cu * 4),
                __ATOMIC_RELAXED, __HIP_MEMORY_SCOPE_AGENT);
        }

        // ---- 2. x-part GEMM (8 MFMAs) under the h-load latency
        f32x4 acc0 = {0,0,0,0}, acc1 = {0,0,0,0}, acc2 = {0,0,0,0}, acc3 = {0,0,0,0};
        #pragma unroll
        for (int ks = 0; ks < 8; ks += 4) {
            f16x8 a0 = *(const f16x8*)(&AldsX[r][p * 256 + (ks + 0) * 32 + a8]);
            acc0 = __builtin_amdgcn_mfma_f32_16x16x32_f16(a0, wregX[ks + 0], acc0, 0, 0, 0);
            f16x8 a1 = *(const f16x8*)(&AldsX[r][p * 256 + (ks + 1) * 32 + a8]);
            acc1 = __builtin_amdgcn_mfma_f32_16x16x32_f16(a1, wregX[ks + 1], acc1, 0, 0, 0);
            f16x8 a2 = *(const f16x8*)(&AldsX[r][p * 256 + (ks + 2) * 32 + a8]);
            acc2 = __builtin_amdgcn_mfma_f32_16x16x32_f16(a2, wregX[ks + 2], acc2, 0, 0, 0);
            f16x8 a3 = *(const f16x8*)(&AldsX[r][p * 256 + (ks + 3) * 32 + a8]);
            acc3 = __builtin_amdgcn_mfma_f32_16x16x32_f16(a3, wregX[ks + 3], acc3, 0, 0, 0);
        }

        // ---- 3. h regs -> LDS, sync
        #pragma unroll
        for (int i = 0; i < 8; ++i) {
            int ch  = tid + i * 512;
            int row = ch >> 8;
            int cu  = ch & 255;
            *(u64*)(&AldsH[row][cu * 4]) = hreg[i];
        }
        __syncthreads();

        // ---- 4. h-part GEMM (16 MFMAs): h cols p*512 .. p*512+511
        #pragma unroll
        for (int ks = 0; ks < 16; ks += 4) {
            f16x8 a0 = *(const f16x8*)(&AldsH[r][p * 512 + (ks + 0) * 32 + a8]);
            acc0 = __builtin_amdgcn_mfma_f32_16x16x32_f16(a0, wregH[ks + 0], acc0, 0, 0, 0);
            f16x8 a1 = *(const f16x8*)(&AldsH[r][p * 512 + (ks + 1) * 32 + a8]);
            acc1 = __builtin_amdgcn_mfma_f32_16x16x32_f16(a1, wregH[ks + 1], acc1, 0, 0, 0);
            f16x8 a2 = *(const f16x8*)(&AldsH[r][p * 512 + (ks + 2) * 32 + a8]);
            acc2 = __builtin_amdgcn_mfma_f32_16x16x32_f16(a2, wregH[ks + 2], acc2, 0, 0, 0);
            f16x8 a3 = *(const f16x8*)(&AldsH[r][p * 512 + (ks + 3) * 32 + a8]);
            acc3 = __builtin_amdgcn_mfma_f32_16x16x32_f16(a3, wregH[ks + 3], acc3, 0, 0, 0);
        }
        f32x4 z = (acc0 + acc1) + (acc2 + acc3);

        // ---- C/D layout: col = lane&15, row = (lane>>4)*4 + rr
        #pragma unroll
        for (int rr = 0; rr < 4; ++rr)
            zlds[wave][(lane >> 4) * 4 + rr][lane & 15] = z[rr];
        __syncthreads();

        // ---- fused gates + state update (threads 0..255; sum both K-parts)
        float nh = 0.f;
        if (tid < 256) {
            float zi = zlds[0][bl][jj] + zlds[4][bl][jj] + bi;
            float zf = zlds[1][bl][jj] + zlds[5][bl][jj] + bff;
            float zg = zlds[2][bl][jj] + zlds[6][bl][jj] + bg;
            float zo = zlds[3][bl][jj] + zlds[7][bl][jj] + bo;
            float ig = fsigmoid(zi);
            float fg = fsigmoid(zf);
            float gg = ftanh(zg);
            float og = fsigmoid(zo);
            float nc = fg * c + ig * gg;
            float th = ftanh(nc);
            nh = og * th;
            c = nc;

            // h-store only (the inter-block dependency); out deferred to spin
            unsigned hv = (unsigned)__builtin_bit_cast(unsigned short, (f16)nh);
            unsigned h1 = __shfl_xor(hv, 1);
            unsigned h2 = __shfl_xor(hv, 2);
            unsigned h3 = __shfl_xor(hv, 3);
            if ((jj & 3) == 0) {
                u64 pk = (u64)hv | ((u64)h1 << 16) | ((u64)h2 << 32) | ((u64)h3 << 48);
                __hip_atomic_store(
                    (u64*)(hbuf + (size_t)((t + 1) & 1) * (B_ * H_)
                                + (size_t)(b0 + bl) * H_ + ng * 16 + jj),
                    pk, __ATOMIC_RELAXED, __HIP_MEMORY_SCOPE_AGENT);
            }
        }

        // ---- barrier + spin-window work (persistent mode only)
        if (t + 1 < t1) {
            __syncthreads();   // drains h-stores (out not yet issued)
            if (tid == 0)      // arrive
                __hip_atomic_fetch_add(mycnt, 1u, __ATOMIC_RELAXED,
                                       __HIP_MEMORY_SCOPE_AGENT);
            if (tid < 256)     // out-store completes during the spin
                out[((size_t)(b0 + bl) * T_ + t) * H_ + ng * 16 + jj] = nh;
            if (tid >= 64)     // waves 1..7: stage x_{t+1}
                stage_x(t + 1, 64, 448);
            if (tid == 0) {    // poll
                const unsigned target = 64u * (unsigned)(t + 1);
                while (__hip_atomic_load(mycnt, __ATOMIC_RELAXED,
                                         __HIP_MEMORY_SCOPE_AGENT) < target)
                    __builtin_amdgcn_s_sleep(1);
            }
            __syncthreads();
        } else if (tid < 256) {
            out[((size_t)(b0 + bl) * T_ + t) * H_ + ng * 16 + jj] = nh;
        }
    }
    if (tid < 256) cbuf[cidx] = c;   // persist cell state across span launches
}

// ---------------------------------------------------------------------------
extern "C" void kernel_launch(void* const* d_in, const int* in_sizes, int n_in,
                              void* d_out, int out_size, void* d_ws, size_t ws_size,
                              hipStream_t stream) {
    const float* x    = (const float*)d_in[0];
    const float* Wi   = (const float*)d_in[1];
    const float* Wh   = (const float*)d_in[2];
    const float* bias = (const float*)d_in[3];
    float* out = (float*)d_out;

    // workspace: Wt | hbuf(2 banks) | cbuf | counters
    const size_t wt_bytes = (size_t)ZC_ * K_ * sizeof(f16);    // 12,582,912
    const size_t hb_bytes = (size_t)2 * B_ * H_ * sizeof(f16); //    262,144
    const size_t cb_bytes = (size_t)B_ * H_ * sizeof(float);   //    262,144
    const size_t cn_bytes = 4096;
    if (ws_size < wt_bytes + hb_bytes + cb_bytes + cn_bytes) return;

    f16*      Wt   = (f16*)d_ws;
    f16*      hbuf = (f16*)((char*)d_ws + wt_bytes);
    float*    cbuf = (float*)((char*)d_ws + wt_bytes + hb_bytes);
    unsigned* cnt  = (unsigned*)((char*)d_ws + wt_bytes + hb_bytes + cb_bytes);

    // zero hbuf + cbuf + counters (contiguous region)
    const int n16 = (int)((hb_bytes + cb_bytes + cn_bytes) / 16);
    init_state<<<(n16 + 255) / 256, 256, 0, stream>>>((uint4*)hbuf, n16);
    build_wt<<<dim3(ZC_ / 64, K_ / 64), 256, 0, stream>>>(Wi, Wh, Wt);

    int t0 = 0, t1 = T_;
    void* args[] = { (void*)&x, (void*)&Wt, (void*)&bias, (void*)&hbuf,
                     (void*)&cbuf, (void*)&cnt, (void*)&out, (void*)&t0, (void*)&t1 };
    hipError_t e = hipLaunchCooperativeKernel((const void*)lstm_span,
                                              dim3(256), dim3(512), args, 0, stream);
    if (e != hipSuccess) {
        (void)hipGetLastError();
        // fallback: one regular launch per timestep (no in-kernel barrier)
        for (int t = 0; t < T_; ++t) {
            lstm_span<<<256, 512, 0, stream>>>(x, Wt, bias, hbuf, cbuf, cnt, out, t, t + 1);
        }
    }
}